// Round 6
// baseline (3320.663 us; speedup 1.0000x reference)
//
#include <hip/hip_runtime.h>
#include <hip/hip_bf16.h>
#include <hip/hip_fp16.h>

// ---------------------------------------------------------------------------
// GRU forward, MI355X.
//   B=32, L=2048, D=256, H=256, 3H=768.
//   Phase 0: convert x,W_ih -> bf16 ; W_hh -> f16
//   Phase 1: xg = x @ W_ih^T + b_ih  via MFMA bf16 16x16x32, 128x128 tiles
//   Phase 2: persistent recurrence, 1 WG per batch (32 WGs).
//     ROUND-6 CHANGE: asm volatile("":"+v"(w)) PIN on each of the 48 named
//     h8 weight values after load. Evidence rounds 3-5: VGPR_Count stuck at
//     108-116 even with waves_per_eu(2,2) active (SGPR 32->112 proves attr
//     applied) => compiler SINKS the weight loads into the loop (per-step L2
//     reloads), it never budget-spilled. The asm barrier forces the loads to
//     materialize pre-loop and stay live. Inner loop = round-5 readlane/SGPR
//     form (VALU-bound once resident: ~1280 cy/step model).
// ---------------------------------------------------------------------------

typedef _Float16 h2v __attribute__((ext_vector_type(2)));
typedef _Float16 h8  __attribute__((ext_vector_type(8)));
typedef __attribute__((ext_vector_type(8))) short s8v;
typedef __attribute__((ext_vector_type(4))) float f4v;

// literal-index pair extraction: h8 is 4 VGPRs, pair k is exactly VGPR k
#define PAIR(v, k) __builtin_shufflevector((v), (v), 2 * (k), 2 * (k) + 1)

// ---------------- converts ----------------

__device__ __forceinline__ unsigned short f2bf_rne(unsigned u) {
  return (unsigned short)((u + 0x7FFFu + ((u >> 16) & 1u)) >> 16);
}

__global__ void cvt_bf16_k(const float* __restrict__ s, unsigned short* __restrict__ d, int n8) {
  int i = blockIdx.x * blockDim.x + threadIdx.x;
  int st = gridDim.x * blockDim.x;
  const uint4* sp = (const uint4*)s;
  for (; i < n8; i += st) {
    uint4 a = sp[2 * i], b = sp[2 * i + 1];
    union { unsigned short us[8]; uint4 u; } o;
    o.us[0] = f2bf_rne(a.x); o.us[1] = f2bf_rne(a.y);
    o.us[2] = f2bf_rne(a.z); o.us[3] = f2bf_rne(a.w);
    o.us[4] = f2bf_rne(b.x); o.us[5] = f2bf_rne(b.y);
    o.us[6] = f2bf_rne(b.z); o.us[7] = f2bf_rne(b.w);
    ((uint4*)d)[i] = o.u;
  }
}

__global__ void cvt_f16_k(const float* __restrict__ s, __half* __restrict__ d, int n8) {
  int i = blockIdx.x * blockDim.x + threadIdx.x;
  int st = gridDim.x * blockDim.x;
  const float4* sp = (const float4*)s;
  for (; i < n8; i += st) {
    float4 a = sp[2 * i], b = sp[2 * i + 1];
    union { uint4 u; __half2 h[4]; } o;
    o.h[0] = __floats2half2_rn(a.x, a.y);
    o.h[1] = __floats2half2_rn(a.z, a.w);
    o.h[2] = __floats2half2_rn(b.x, b.y);
    o.h[3] = __floats2half2_rn(b.z, b.w);
    ((uint4*)d)[i] = o.u;
  }
}

// ---------------- phase 1: xg GEMM (bf16 MFMA) ----------------
#define BT 48

__global__ __launch_bounds__(256) void gemm_xg(
    const unsigned short* __restrict__ X, const unsigned short* __restrict__ W,
    const float* __restrict__ bias, __half* __restrict__ XG) {
  __shared__ unsigned short As[128 * BT];
  __shared__ unsigned short Bs[128 * BT];
  const int tid = threadIdx.x;
  const int bm = blockIdx.x, bn = blockIdx.y;
  const int w = tid >> 6, l = tid & 63;
  const int wr = (w >> 1) * 64, wc = (w & 1) * 64;

  f4v acc[4][4];
#pragma unroll
  for (int a = 0; a < 4; ++a)
#pragma unroll
    for (int b = 0; b < 4; ++b) {
      acc[a][b][0] = 0.f; acc[a][b][1] = 0.f; acc[a][b][2] = 0.f; acc[a][b][3] = 0.f;
    }

  const long arow0 = (long)bm * 128;
  const int brow0 = bn * 128;

  for (int kb = 0; kb < 256; kb += 32) {
#pragma unroll
    for (int cc = 0; cc < 2; ++cc) {
      int c = tid + cc * 256;
      int row = c >> 2, part = c & 3;
      uint4 av = *(const uint4*)(X + (arow0 + row) * 256 + kb + part * 8);
      *(uint4*)(&As[row * BT + part * 8]) = av;
      uint4 bv = *(const uint4*)(W + (long)(brow0 + row) * 256 + kb + part * 8);
      *(uint4*)(&Bs[row * BT + part * 8]) = bv;
    }
    __syncthreads();

    const int lr = l & 15, kg = (l >> 4) * 8;
    s8v af[4], bf[4];
#pragma unroll
    for (int mi = 0; mi < 4; ++mi) af[mi] = *(const s8v*)(&As[(wr + mi * 16 + lr) * BT + kg]);
#pragma unroll
    for (int ni = 0; ni < 4; ++ni) bf[ni] = *(const s8v*)(&Bs[(wc + ni * 16 + lr) * BT + kg]);
#pragma unroll
    for (int mi = 0; mi < 4; ++mi)
#pragma unroll
      for (int ni = 0; ni < 4; ++ni)
        acc[mi][ni] = __builtin_amdgcn_mfma_f32_16x16x32_bf16(af[mi], bf[ni], acc[mi][ni], 0, 0, 0);
    __syncthreads();
  }

  const int lr = l & 15, rg = (l >> 4) * 4;
#pragma unroll
  for (int mi = 0; mi < 4; ++mi)
#pragma unroll
    for (int ni = 0; ni < 4; ++ni) {
      int gcol = bn * 128 + wc + ni * 16 + lr;
      float bv = bias[gcol];
#pragma unroll
      for (int r = 0; r < 4; ++r) {
        long grow = arow0 + wr + mi * 16 + rg + r;
        XG[grow * 768 + gcol] = __float2half(acc[mi][ni][r] + bv);
      }
    }
}

// ---------------- phase 2: recurrence ----------------

__device__ __forceinline__ float fdot2f(h2v a, h2v b, float c) {
#if __has_builtin(__builtin_amdgcn_fdot2)
  return __builtin_amdgcn_fdot2(a, b, c, false);
#else
  return c + (float)a.x * (float)b.x + (float)a.y * (float)b.y;
#endif
}

__device__ __forceinline__ float rcp_fast(float x) {
#if __has_builtin(__builtin_amdgcn_rcpf)
  return __builtin_amdgcn_rcpf(x);
#else
  return 1.f / x;
#endif
}

#define FOR16A(M) M(0) M(1) M(2) M(3) M(4) M(5) M(6) M(7) \
                  M(8) M(9) M(10) M(11) M(12) M(13) M(14) M(15)
#define FOR16B(M) M(16) M(17) M(18) M(19) M(20) M(21) M(22) M(23) \
                  M(24) M(25) M(26) M(27) M(28) M(29) M(30) M(31)
#define FOR16C(M) M(16,0) M(17,1) M(18,2) M(19,3) M(20,4) M(21,5) M(22,6) M(23,7) \
                  M(24,8) M(25,9) M(26,10) M(27,11) M(28,12) M(29,13) M(30,14) M(31,15)

// chunk J covers h[8J..8J+8) = SGPR pairs {hpa,hpb,hpc,hpd}_J
#define RLCHUNK(J) \
  unsigned hpa_##J, hpb_##J, hpc_##J, hpd_##J; \
  asm("v_readlane_b32 %0, %1, %2" : "=s"(hpa_##J) : "v"(hd.x), "i"(2 * (J))); \
  asm("v_readlane_b32 %0, %1, %2" : "=s"(hpb_##J) : "v"(hd.y), "i"(2 * (J))); \
  asm("v_readlane_b32 %0, %1, %2" : "=s"(hpc_##J) : "v"(hd.x), "i"(2 * (J) + 1)); \
  asm("v_readlane_b32 %0, %1, %2" : "=s"(hpd_##J) : "v"(hd.y), "i"(2 * (J) + 1));

#define DOTF(J) \
  a0 = fdot2f(__builtin_bit_cast(h2v, hpa_##J), PAIR(wf##J, 0), a0); \
  a1 = fdot2f(__builtin_bit_cast(h2v, hpb_##J), PAIR(wf##J, 1), a1); \
  a0 = fdot2f(__builtin_bit_cast(h2v, hpc_##J), PAIR(wf##J, 2), a0); \
  a1 = fdot2f(__builtin_bit_cast(h2v, hpd_##J), PAIR(wf##J, 3), a1);

#define DOTN(J, U) \
  b0 = fdot2f(__builtin_bit_cast(h2v, hpa_##J), PAIR(uh##U, 0), b0); \
  b1 = fdot2f(__builtin_bit_cast(h2v, hpb_##J), PAIR(uh##U, 1), b1); \
  b0 = fdot2f(__builtin_bit_cast(h2v, hpc_##J), PAIR(uh##U, 2), b0); \
  b1 = fdot2f(__builtin_bit_cast(h2v, hpd_##J), PAIR(uh##U, 3), b1);

#define CHF(J)     RLCHUNK(J) DOTF(J)
#define CHN(J)     RLCHUNK(J) DOTF(J) DOTN(J, J)
#define CHN2(J, U) RLCHUNK(J) DOTF(J) DOTN(J, U)

// 32 blocks x 512 threads (8 waves). grp = tid>>8 (wave-uniform).
//  grp0 (tid 0..255):   update row i (full K)  + new-row(512+i) k in [0,128)
//  grp1 (tid 256..511): reset  row 256+i (full K) + new-row(512+i) k in [128,256)
__global__ __launch_bounds__(512)
__attribute__((amdgpu_waves_per_eu(2, 2)))
void gru_rec(
    const __half* __restrict__ Whh, const __half* __restrict__ XG,
    float* __restrict__ Y) {
  const int b = blockIdx.x;
  const int tid = threadIdx.x;
  const int i = tid & 255;
  const int grp = tid >> 8;
  const int lane = tid & 63;

  __shared__ __align__(16) __half hl[256];
  __shared__ float r_l[256];
  __shared__ float p1_l[256];

  const uint4* wrow = (const uint4*)(Whh + (long)tid * 256);
  const uint4* wnew = (const uint4*)(Whh + (long)(512 + i) * 256 + grp * 128);

  // 48 named weight registers (192 VGPRs) — no arrays, no alloca.
#define DECL_WF(J) h8 wf##J = __builtin_bit_cast(h8, wrow[(J)]);
#define DECL_UH(J) h8 uh##J = __builtin_bit_cast(h8, wnew[(J)]);
  FOR16A(DECL_WF)
  FOR16B(DECL_WF)
  FOR16A(DECL_UH)
#undef DECL_WF
#undef DECL_UH

  // PIN: force every weight value to materialize in VGPRs HERE and stay
  // live across the loop — the asm use makes sinking the load illegal.
#define PIN8(A,B,C,D,E,F,G,H) \
  asm volatile("" : "+v"(A), "+v"(B), "+v"(C), "+v"(D), \
                    "+v"(E), "+v"(F), "+v"(G), "+v"(H));
  PIN8(wf0, wf1, wf2, wf3, wf4, wf5, wf6, wf7)
  PIN8(wf8, wf9, wf10, wf11, wf12, wf13, wf14, wf15)
  PIN8(wf16, wf17, wf18, wf19, wf20, wf21, wf22, wf23)
  PIN8(wf24, wf25, wf26, wf27, wf28, wf29, wf30, wf31)
  PIN8(uh0, uh1, uh2, uh3, uh4, uh5, uh6, uh7)
  PIN8(uh8, uh9, uh10, uh11, uh12, uh13, uh14, uh15)
#undef PIN8

  if (grp == 0) hl[i] = __float2half(0.f);
  float h_old = 0.f;
  __syncthreads();

  const long base = (long)b * 2048 * 768;
  const long ybase = (long)b * 2048 * 256;
  const int colA = grp ? (256 + i) : i;

  __half va_c = XG[base + colA];
  __half vb_c = __float2half(0.f);
  if (!grp) vb_c = XG[base + 512 + i];

  for (int t = 0; t < 2048; ++t) {
    const long nx = base + (long)(t + 1 < 2048 ? t + 1 : 2047) * 768;
    __half va_n = XG[nx + colA];
    __half vb_n = vb_c;
    if (!grp) vb_n = XG[nx + 512 + i];

    // one ds_read_b64 per wave: lane l holds h[4l..4l+4)
    uint2 hd = *(const uint2*)(&hl[lane * 4]);

    float a0 = 0.f, a1 = 0.f, b0 = 0.f, b1 = 0.f;
    if (!grp) {
      FOR16A(CHN)   // chunks 0-15: full-row + new-row (k-half 0)
      FOR16B(CHF)   // chunks 16-31: full-row only
    } else {
      FOR16A(CHF)   // chunks 0-15: full-row only
      FOR16C(CHN2)  // chunks 16-31: full-row + new-row (k-half 1, uh0..uh15)
    }

    const float dF = a0 + a1;   // h_u (grp0) / h_r (grp1)
    const float dH = b0 + b1;   // partial h_n
    const float xv = __half2float(va_c);

    if (grp) {
      float r = rcp_fast(1.f + __expf(-(xv + dF)));
      r_l[i] = r;
      p1_l[i] = dH;
    }
    __syncthreads();
    if (!grp) {
      float z = rcp_fast(1.f + __expf(-(xv + dF)));
      float hn = dH + p1_l[i];
      float pre = __half2float(vb_c) + r_l[i] * hn;
      float e = __expf(2.f * pre);
      float n = 1.f - 2.f * rcp_fast(1.f + e);
      float hnew = z * h_old + (1.f - z) * n;
      Y[ybase + (long)t * 256 + i] = hnew;
      hl[i] = __float2half(hnew);
      h_old = hnew;
    }
    __syncthreads();
    va_c = va_n;
    vb_c = vb_n;
  }
}

// ---------------- launch ----------------

extern "C" void kernel_launch(void* const* d_in, const int* in_sizes, int n_in,
                              void* d_out, int out_size, void* d_ws, size_t ws_size,
                              hipStream_t stream) {
  const float* x   = (const float*)d_in[0];  // [32,2048,256]
  const float* Wih = (const float*)d_in[1];  // [768,256]
  const float* bih = (const float*)d_in[2];  // [768]
  const float* Whh = (const float*)d_in[3];  // [768,256]
  float* Y = (float*)d_out;                  // [32,2048,256]

  char* ws = (char*)d_ws;
  unsigned short* x16   = (unsigned short*)ws;
  unsigned short* wih16 = (unsigned short*)(ws + 33554432);
  __half*         whh16 = (__half*)(ws + 33554432 + 393216);
  __half*         xg16  = (__half*)(ws + 33554432 + 2 * 393216);

  cvt_bf16_k<<<2048, 256, 0, stream>>>(x, x16, 16777216 / 8);
  cvt_bf16_k<<<96, 256, 0, stream>>>(Wih, wih16, 196608 / 8);
  cvt_f16_k<<<96, 256, 0, stream>>>(Whh, whh16, 196608 / 8);

  dim3 g(512, 6);
  gemm_xg<<<g, 256, 0, stream>>>(x16, wih16, bih, xg16);

  gru_rec<<<32, 512, 0, stream>>>(whh16, xg16, Y);
}

// Round 7
// 3275.774 us; speedup vs baseline: 1.0137x; 1.0137x over previous
//
#include <hip/hip_runtime.h>
#include <hip/hip_bf16.h>
#include <hip/hip_fp16.h>

// ---------------------------------------------------------------------------
// GRU forward, MI355X.
//   B=32, L=2048, D=256, H=256, 3H=768.
//   Phase 0: convert x,W_ih -> bf16 ; W_hh -> f16
//   Phase 1: xg = x @ W_ih^T + b_ih  via MFMA bf16 16x16x32, 128x128 tiles
//   Phase 2: persistent recurrence, 1 WG per batch (32 WGs).
//     ROUND-7 CHANGE: weights loaded via VOLATILE INLINE-ASM
//     global_load_dwordx4 ("=v" outputs) + one s_waitcnt vmcnt(0).
//     Evidence R3-R6: VGPR stuck at 108-116 because loads from const
//     __restrict memory are REMATERIALIZABLE -> RA re-executes them in-loop
//     (L2 weight streaming at ~100 B/cy/CU == measured 3020 cy/step) instead
//     of keeping 192 VGPRs live. A volatile-asm result cannot be remat'd;
//     with waves_per_eu(2,2) budget=256 >= demand ~232, so the RA's cheapest
//     legal choice is true residency. Inner loop identical to R5/R6.
// ---------------------------------------------------------------------------

typedef _Float16 h2v __attribute__((ext_vector_type(2)));
typedef _Float16 h8  __attribute__((ext_vector_type(8)));
typedef __attribute__((ext_vector_type(8))) short s8v;
typedef __attribute__((ext_vector_type(4))) float f4v;

// literal-index pair extraction: h8 is 4 VGPRs, pair k is exactly VGPR k
#define PAIR(v, k) __builtin_shufflevector((v), (v), 2 * (k), 2 * (k) + 1)

// ---------------- converts ----------------

__device__ __forceinline__ unsigned short f2bf_rne(unsigned u) {
  return (unsigned short)((u + 0x7FFFu + ((u >> 16) & 1u)) >> 16);
}

__global__ void cvt_bf16_k(const float* __restrict__ s, unsigned short* __restrict__ d, int n8) {
  int i = blockIdx.x * blockDim.x + threadIdx.x;
  int st = gridDim.x * blockDim.x;
  const uint4* sp = (const uint4*)s;
  for (; i < n8; i += st) {
    uint4 a = sp[2 * i], b = sp[2 * i + 1];
    union { unsigned short us[8]; uint4 u; } o;
    o.us[0] = f2bf_rne(a.x); o.us[1] = f2bf_rne(a.y);
    o.us[2] = f2bf_rne(a.z); o.us[3] = f2bf_rne(a.w);
    o.us[4] = f2bf_rne(b.x); o.us[5] = f2bf_rne(b.y);
    o.us[6] = f2bf_rne(b.z); o.us[7] = f2bf_rne(b.w);
    ((uint4*)d)[i] = o.u;
  }
}

__global__ void cvt_f16_k(const float* __restrict__ s, __half* __restrict__ d, int n8) {
  int i = blockIdx.x * blockDim.x + threadIdx.x;
  int st = gridDim.x * blockDim.x;
  const float4* sp = (const float4*)s;
  for (; i < n8; i += st) {
    float4 a = sp[2 * i], b = sp[2 * i + 1];
    union { uint4 u; __half2 h[4]; } o;
    o.h[0] = __floats2half2_rn(a.x, a.y);
    o.h[1] = __floats2half2_rn(a.z, a.w);
    o.h[2] = __floats2half2_rn(b.x, b.y);
    o.h[3] = __floats2half2_rn(b.z, b.w);
    ((uint4*)d)[i] = o.u;
  }
}

// ---------------- phase 1: xg GEMM (bf16 MFMA) ----------------
#define BT 48

__global__ __launch_bounds__(256) void gemm_xg(
    const unsigned short* __restrict__ X, const unsigned short* __restrict__ W,
    const float* __restrict__ bias, __half* __restrict__ XG) {
  __shared__ unsigned short As[128 * BT];
  __shared__ unsigned short Bs[128 * BT];
  const int tid = threadIdx.x;
  const int bm = blockIdx.x, bn = blockIdx.y;
  const int w = tid >> 6, l = tid & 63;
  const int wr = (w >> 1) * 64, wc = (w & 1) * 64;

  f4v acc[4][4];
#pragma unroll
  for (int a = 0; a < 4; ++a)
#pragma unroll
    for (int b = 0; b < 4; ++b) {
      acc[a][b][0] = 0.f; acc[a][b][1] = 0.f; acc[a][b][2] = 0.f; acc[a][b][3] = 0.f;
    }

  const long arow0 = (long)bm * 128;
  const int brow0 = bn * 128;

  for (int kb = 0; kb < 256; kb += 32) {
#pragma unroll
    for (int cc = 0; cc < 2; ++cc) {
      int c = tid + cc * 256;
      int row = c >> 2, part = c & 3;
      uint4 av = *(const uint4*)(X + (arow0 + row) * 256 + kb + part * 8);
      *(uint4*)(&As[row * BT + part * 8]) = av;
      uint4 bv = *(const uint4*)(W + (long)(brow0 + row) * 256 + kb + part * 8);
      *(uint4*)(&Bs[row * BT + part * 8]) = bv;
    }
    __syncthreads();

    const int lr = l & 15, kg = (l >> 4) * 8;
    s8v af[4], bf[4];
#pragma unroll
    for (int mi = 0; mi < 4; ++mi) af[mi] = *(const s8v*)(&As[(wr + mi * 16 + lr) * BT + kg]);
#pragma unroll
    for (int ni = 0; ni < 4; ++ni) bf[ni] = *(const s8v*)(&Bs[(wc + ni * 16 + lr) * BT + kg]);
#pragma unroll
    for (int mi = 0; mi < 4; ++mi)
#pragma unroll
      for (int ni = 0; ni < 4; ++ni)
        acc[mi][ni] = __builtin_amdgcn_mfma_f32_16x16x32_bf16(af[mi], bf[ni], acc[mi][ni], 0, 0, 0);
    __syncthreads();
  }

  const int lr = l & 15, rg = (l >> 4) * 4;
#pragma unroll
  for (int mi = 0; mi < 4; ++mi)
#pragma unroll
    for (int ni = 0; ni < 4; ++ni) {
      int gcol = bn * 128 + wc + ni * 16 + lr;
      float bv = bias[gcol];
#pragma unroll
      for (int r = 0; r < 4; ++r) {
        long grow = arow0 + wr + mi * 16 + rg + r;
        XG[grow * 768 + gcol] = __float2half(acc[mi][ni][r] + bv);
      }
    }
}

// ---------------- phase 2: recurrence ----------------

__device__ __forceinline__ float fdot2f(h2v a, h2v b, float c) {
#if __has_builtin(__builtin_amdgcn_fdot2)
  return __builtin_amdgcn_fdot2(a, b, c, false);
#else
  return c + (float)a.x * (float)b.x + (float)a.y * (float)b.y;
#endif
}

__device__ __forceinline__ float rcp_fast(float x) {
#if __has_builtin(__builtin_amdgcn_rcpf)
  return __builtin_amdgcn_rcpf(x);
#else
  return 1.f / x;
#endif
}

#define FOR16A(M) M(0) M(1) M(2) M(3) M(4) M(5) M(6) M(7) \
                  M(8) M(9) M(10) M(11) M(12) M(13) M(14) M(15)
#define FOR16B(M) M(16) M(17) M(18) M(19) M(20) M(21) M(22) M(23) \
                  M(24) M(25) M(26) M(27) M(28) M(29) M(30) M(31)
#define FOR16C(M) M(16,0) M(17,1) M(18,2) M(19,3) M(20,4) M(21,5) M(22,6) M(23,7) \
                  M(24,8) M(25,9) M(26,10) M(27,11) M(28,12) M(29,13) M(30,14) M(31,15)

// chunk J covers h[8J..8J+8) = SGPR pairs {hpa,hpb,hpc,hpd}_J
#define RLCHUNK(J) \
  unsigned hpa_##J, hpb_##J, hpc_##J, hpd_##J; \
  asm("v_readlane_b32 %0, %1, %2" : "=s"(hpa_##J) : "v"(hd.x), "i"(2 * (J))); \
  asm("v_readlane_b32 %0, %1, %2" : "=s"(hpb_##J) : "v"(hd.y), "i"(2 * (J))); \
  asm("v_readlane_b32 %0, %1, %2" : "=s"(hpc_##J) : "v"(hd.x), "i"(2 * (J) + 1)); \
  asm("v_readlane_b32 %0, %1, %2" : "=s"(hpd_##J) : "v"(hd.y), "i"(2 * (J) + 1));

#define DOTF(J) \
  a0 = fdot2f(__builtin_bit_cast(h2v, hpa_##J), PAIR(wf##J, 0), a0); \
  a1 = fdot2f(__builtin_bit_cast(h2v, hpb_##J), PAIR(wf##J, 1), a1); \
  a0 = fdot2f(__builtin_bit_cast(h2v, hpc_##J), PAIR(wf##J, 2), a0); \
  a1 = fdot2f(__builtin_bit_cast(h2v, hpd_##J), PAIR(wf##J, 3), a1);

#define DOTN(J, U) \
  b0 = fdot2f(__builtin_bit_cast(h2v, hpa_##J), PAIR(uh##U, 0), b0); \
  b1 = fdot2f(__builtin_bit_cast(h2v, hpb_##J), PAIR(uh##U, 1), b1); \
  b0 = fdot2f(__builtin_bit_cast(h2v, hpc_##J), PAIR(uh##U, 2), b0); \
  b1 = fdot2f(__builtin_bit_cast(h2v, hpd_##J), PAIR(uh##U, 3), b1);

#define CHF(J)     RLCHUNK(J) DOTF(J)
#define CHN(J)     RLCHUNK(J) DOTF(J) DOTN(J, J)
#define CHN2(J, U) RLCHUNK(J) DOTF(J) DOTN(J, U)

// 32 blocks x 512 threads (8 waves). grp = tid>>8 (wave-uniform).
//  grp0 (tid 0..255):   update row i (full K)  + new-row(512+i) k in [0,128)
//  grp1 (tid 256..511): reset  row 256+i (full K) + new-row(512+i) k in [128,256)
__global__ __launch_bounds__(512)
__attribute__((amdgpu_waves_per_eu(2, 2)))
void gru_rec(
    const __half* __restrict__ Whh, const __half* __restrict__ XG,
    float* __restrict__ Y) {
  const int b = blockIdx.x;
  const int tid = threadIdx.x;
  const int i = tid & 255;
  const int grp = tid >> 8;
  const int lane = tid & 63;

  __shared__ __align__(16) __half hl[256];
  __shared__ float r_l[256];
  __shared__ float p1_l[256];

  const char* wrow = (const char*)(Whh + (long)tid * 256);
  const char* wnew = (const char*)(Whh + (long)(512 + i) * 256 + grp * 128);

  // 48 weight chunks loaded via VOLATILE asm -> results are opaque SSA
  // values the RA cannot rematerialize: they must stay in VGPRs.
#define DECL_WF(J) h8 wf##J; { const void* aP = wrow + 16 * (J); \
  asm volatile("global_load_dwordx4 %0, %1, off" : "=v"(wf##J) : "v"(aP)); }
#define DECL_UH(J) h8 uh##J; { const void* aP = wnew + 16 * (J); \
  asm volatile("global_load_dwordx4 %0, %1, off" : "=v"(uh##J) : "v"(aP)); }
  FOR16A(DECL_WF)
  FOR16B(DECL_WF)
  FOR16A(DECL_UH)
#undef DECL_WF
#undef DECL_UH
  asm volatile("s_waitcnt vmcnt(0)" ::: "memory");

  if (grp == 0) hl[i] = __float2half(0.f);
  float h_old = 0.f;
  __syncthreads();

  const long base = (long)b * 2048 * 768;
  const long ybase = (long)b * 2048 * 256;
  const int colA = grp ? (256 + i) : i;

  __half va_c = XG[base + colA];
  __half vb_c = __float2half(0.f);
  if (!grp) vb_c = XG[base + 512 + i];

  for (int t = 0; t < 2048; ++t) {
    const long nx = base + (long)(t + 1 < 2048 ? t + 1 : 2047) * 768;
    __half va_n = XG[nx + colA];
    __half vb_n = vb_c;
    if (!grp) vb_n = XG[nx + 512 + i];

    // one ds_read_b64 per wave: lane l holds h[4l..4l+4)
    uint2 hd = *(const uint2*)(&hl[lane * 4]);

    float a0 = 0.f, a1 = 0.f, b0 = 0.f, b1 = 0.f;
    if (!grp) {
      FOR16A(CHN)   // chunks 0-15: full-row + new-row (k-half 0)
      FOR16B(CHF)   // chunks 16-31: full-row only
    } else {
      FOR16A(CHF)   // chunks 0-15: full-row only
      FOR16C(CHN2)  // chunks 16-31: full-row + new-row (k-half 1, uh0..uh15)
    }

    const float dF = a0 + a1;   // h_u (grp0) / h_r (grp1)
    const float dH = b0 + b1;   // partial h_n
    const float xv = __half2float(va_c);

    if (grp) {
      float r = rcp_fast(1.f + __expf(-(xv + dF)));
      r_l[i] = r;
      p1_l[i] = dH;
    }
    __syncthreads();
    if (!grp) {
      float z = rcp_fast(1.f + __expf(-(xv + dF)));
      float hn = dH + p1_l[i];
      float pre = __half2float(vb_c) + r_l[i] * hn;
      float e = __expf(2.f * pre);
      float n = 1.f - 2.f * rcp_fast(1.f + e);
      float hnew = z * h_old + (1.f - z) * n;
      Y[ybase + (long)t * 256 + i] = hnew;
      hl[i] = __float2half(hnew);
      h_old = hnew;
    }
    __syncthreads();
    va_c = va_n;
    vb_c = vb_n;
  }
}

// ---------------- launch ----------------

extern "C" void kernel_launch(void* const* d_in, const int* in_sizes, int n_in,
                              void* d_out, int out_size, void* d_ws, size_t ws_size,
                              hipStream_t stream) {
  const float* x   = (const float*)d_in[0];  // [32,2048,256]
  const float* Wih = (const float*)d_in[1];  // [768,256]
  const float* bih = (const float*)d_in[2];  // [768]
  const float* Whh = (const float*)d_in[3];  // [768,256]
  float* Y = (float*)d_out;                  // [32,2048,256]

  char* ws = (char*)d_ws;
  unsigned short* x16   = (unsigned short*)ws;
  unsigned short* wih16 = (unsigned short*)(ws + 33554432);
  __half*         whh16 = (__half*)(ws + 33554432 + 393216);
  __half*         xg16  = (__half*)(ws + 33554432 + 2 * 393216);

  cvt_bf16_k<<<2048, 256, 0, stream>>>(x, x16, 16777216 / 8);
  cvt_bf16_k<<<96, 256, 0, stream>>>(Wih, wih16, 196608 / 8);
  cvt_f16_k<<<96, 256, 0, stream>>>(Whh, whh16, 196608 / 8);

  dim3 g(512, 6);
  gemm_xg<<<g, 256, 0, stream>>>(x16, wih16, bih, xg16);

  gru_rec<<<32, 512, 0, stream>>>(whh16, xg16, Y);
}